// Round 16
// baseline (4512.062 us; speedup 1.0000x reference)
//
#include <hip/hip_runtime.h>
#include <hip/hip_bf16.h>
#include <stdint.h>
#include <stddef.h>

// Problem sizes (fixed)
#define HID   1024
#define NB    64
#define SEQ   512
#define G3    3072   // 3*HID
#define EMB   512
#define LAT   64

typedef __attribute__((ext_vector_type(4))) float f32x4;
typedef __attribute__((ext_vector_type(8))) short bfrag;  // 8 bf16 (4 VGPRs)
typedef unsigned long long ull;

// ---------- helpers ----------
__device__ __forceinline__ unsigned short f2bf(float x) {   // RNE f32->bf16
  union { float f; unsigned u; } v; v.f = x;
  unsigned u = v.u + 0x7fffu + ((v.u >> 16) & 1u);
  return (unsigned short)(u >> 16);
}
__device__ __forceinline__ float bf2f(short s) {
  union { unsigned u; float f; } v; v.u = ((unsigned)(unsigned short)s) << 16;
  return v.f;
}
__device__ __forceinline__ float fsig(float x) {
  return 1.0f / (1.0f + __builtin_exp2f(-1.4426950408889634f * x));
}
__device__ __forceinline__ float ftanh(float x) {
  return 1.0f - 2.0f / (1.0f + __builtin_exp2f(2.8853900817779268f * x));
}
__device__ __forceinline__ void gload_lds16(const void* g, void* l) {
  __builtin_amdgcn_global_load_lds(
      (const __attribute__((address_space(1))) unsigned int*)g,
      (__attribute__((address_space(3))) unsigned int*)l, 16, 0, 0);
}

// ---------- kernel 0: w_ih f32 -> bf16 ----------
__global__ void cvt_wih_kernel(const float* __restrict__ in, short* __restrict__ out) {
  int i = (blockIdx.x * 256 + threadIdx.x) * 8;   // grid sized exactly
  f32x4 a = *(const f32x4*)(in + i);
  f32x4 b = *(const f32x4*)(in + i + 4);
  bfrag o;
  o[0]=(short)f2bf(a[0]); o[1]=(short)f2bf(a[1]); o[2]=(short)f2bf(a[2]); o[3]=(short)f2bf(a[3]);
  o[4]=(short)f2bf(b[0]); o[5]=(short)f2bf(b[1]); o[6]=(short)f2bf(b[2]); o[7]=(short)f2bf(b[3]);
  *(bfrag*)(out + i) = o;
}

// ---------- kernel 1: gx = emb[ids] @ w_ih^T  (bf16 MFMA, fp32 acc, bf16 out) ----------
__global__ void __launch_bounds__(256) gemm_gx_kernel(
    const int* __restrict__ ids, const float* __restrict__ emb,
    const short* __restrict__ wih, short* __restrict__ gx)
{
  const int nt = blockIdx.x, mt = blockIdx.y;
  const int tid = threadIdx.x;
  const int lane = tid & 63, wave = tid >> 6;
  const int wr = wave >> 1, wc = wave & 1;

  __shared__ __align__(16) short A_lds[128 * 48];
  __shared__ __align__(16) short B_lds[128 * 32];
  __shared__ int ids_s[128];

  if (tid < 128) ids_s[tid] = ids[mt * 128 + tid];
  __syncthreads();

  f32x4 acc[4][4];
  #pragma unroll
  for (int i = 0; i < 4; ++i)
    #pragma unroll
    for (int j = 0; j < 4; ++j) acc[i][j] = (f32x4){0.f, 0.f, 0.f, 0.f};

  const int r_stage = tid >> 1;
  const int kh = (tid & 1) * 16;

  #pragma unroll 1
  for (int kc = 0; kc < 16; ++kc) {
    __syncthreads();
    {
      const float* src = emb + (size_t)ids_s[r_stage] * 512 + kc * 32 + kh;
      f32x4 v0 = *(const f32x4*)(src);
      f32x4 v1 = *(const f32x4*)(src + 4);
      f32x4 v2 = *(const f32x4*)(src + 8);
      f32x4 v3 = *(const f32x4*)(src + 12);
      bfrag p0, p1;
      p0[0]=(short)f2bf(v0[0]); p0[1]=(short)f2bf(v0[1]); p0[2]=(short)f2bf(v0[2]); p0[3]=(short)f2bf(v0[3]);
      p0[4]=(short)f2bf(v1[0]); p0[5]=(short)f2bf(v1[1]); p0[6]=(short)f2bf(v1[2]); p0[7]=(short)f2bf(v1[3]);
      p1[0]=(short)f2bf(v2[0]); p1[1]=(short)f2bf(v2[1]); p1[2]=(short)f2bf(v2[2]); p1[3]=(short)f2bf(v2[3]);
      p1[4]=(short)f2bf(v3[0]); p1[5]=(short)f2bf(v3[1]); p1[6]=(short)f2bf(v3[2]); p1[7]=(short)f2bf(v3[3]);
      *(bfrag*)&A_lds[r_stage * 48 + kh]     = p0;
      *(bfrag*)&A_lds[r_stage * 48 + kh + 8] = p1;
    }
    {
      #pragma unroll
      for (int ii = 0; ii < 2; ++ii) {
        int i = wave * 2 + ii;
        const short* src = wih + (size_t)(nt * 128 + i * 16 + (lane >> 2)) * 512
                               + kc * 32 + (lane & 3) * 8;
        gload_lds16((const void*)src, (void*)&B_lds[i * 512]);
      }
    }
    asm volatile("s_waitcnt vmcnt(0)" ::: "memory");
    __syncthreads();

    bfrag a[4], b[4];
    #pragma unroll
    for (int mi = 0; mi < 4; ++mi)
      a[mi] = *(const bfrag*)&A_lds[(wr * 64 + mi * 16 + (lane & 15)) * 48 + (lane >> 4) * 8];
    #pragma unroll
    for (int ni = 0; ni < 4; ++ni)
      b[ni] = *(const bfrag*)&B_lds[(wc * 64 + ni * 16 + (lane & 15)) * 32 + (lane >> 4) * 8];
    #pragma unroll
    for (int mi = 0; mi < 4; ++mi)
      #pragma unroll
      for (int ni = 0; ni < 4; ++ni)
        acc[mi][ni] = __builtin_amdgcn_mfma_f32_16x16x32_bf16(a[mi], b[ni], acc[mi][ni], 0, 0, 0);
  }

  #pragma unroll
  for (int mi = 0; mi < 4; ++mi)
    #pragma unroll
    for (int ni = 0; ni < 4; ++ni)
      #pragma unroll
      for (int r = 0; r < 4; ++r) {
        int m = mt * 128 + wr * 64 + mi * 16 + (lane >> 4) * 4 + r;
        int n = nt * 128 + wc * 64 + ni * 16 + (lane & 15);
        gx[(size_t)m * G3 + n] = (short)f2bf(acc[mi][ni][r]);
      }
}

// ---------- kernel 2: persistent GRU scan — r14 skeleton + epoch-in-data exchange ----------
// 256 WGs x 256 thr (4 waves). WG = (team = bid>>6 owns 16 batch rows,
// cg = bid&63 owns 16 hidden cols). Wave = K-quarter (wfrag[3][8] = 96 VGPRs).
// Exchange format: per cg, 96 qwords; qword(b,j) = epoch<<48 | v(3j+2)<<32 |
// v(3j+1)<<16 | v(3j)  (v = bf16 of col jcol0+c, row b; j=5 holds 1 value).
// 8B stores are single-copy atomic -> validity travels WITH the data:
//  - writer (wave1, after S3): pack 96 qwords from hstg, fire stores. NO
//    drain, NO flag.
//  - reader (each wave, own quarter): batched 24-load sweep, validate epochs
//    == s in regs, re-issue only stale ones per sweep (NOT serial retry).
// WAR safety (= r14's proof): wave kq validates cgs [16kq,16kq+16) at epoch s;
// union over 4 waves = all 64 writers; S2 joins -> publishing h(s+1) implies
// every WG finished staging h(s-1) (same parity). Future epochs impossible by
// the same induction -> exact compare. Base case: memset zeros = epoch 0.
__global__ void __launch_bounds__(256, 1) gru_scan_kernel(
    const short* __restrict__ gx, const float* __restrict__ whh,
    const float* __restrict__ bihp, const float* __restrict__ bhhp,
    ull* __restrict__ hbuf_q, float* __restrict__ hsum)
{
  const int wg   = blockIdx.x;       // 0..255
  const int team = wg >> 6;          // 0..3
  const int cg   = wg & 63;          // col-group
  const int tid  = threadIdx.x;
  const int lane = tid & 63, wave = tid >> 6;   // wave = K-quarter 0..3
  const int bl   = lane & 15;
  const int bsub = (lane >> 4) * 4;
  const int jcol = cg * 16 + bl;
  const int bteam = team * 16;

  __shared__ __align__(16) short h_lds[16 * 1024];   // 32 KB [b][k] swizzled
  __shared__ __align__(16) float part[3 * 3 * 256];  // 9 KB [g][wave-1][lane*4]
  __shared__ __align__(16) short hstg[256];          // 512 B [b][c] exchange order

  // --- weights: 16 cols x 3 gates x K-quarter as B-frags (bf16), 96 VGPRs ---
  bfrag wfrag[3][8];
  #pragma unroll
  for (int g = 0; g < 3; ++g) {
    const float* wrow = whh + (size_t)(g * 1024 + jcol) * 1024 + wave * 256 + (lane >> 4) * 8;
    #pragma unroll
    for (int ks = 0; ks < 8; ++ks) {
      const float* p = wrow + ks * 32;
      f32x4 lo = *(const f32x4*)p;
      f32x4 hi = *(const f32x4*)(p + 4);
      bfrag f;
      f[0]=(short)f2bf(lo[0]); f[1]=(short)f2bf(lo[1]); f[2]=(short)f2bf(lo[2]); f[3]=(short)f2bf(lo[3]);
      f[4]=(short)f2bf(hi[0]); f[5]=(short)f2bf(hi[1]); f[6]=(short)f2bf(hi[2]); f[7]=(short)f2bf(hi[3]);
      wfrag[g][ks] = f;
    }
  }
  float bih_r[3], bhh_r[3];
  #pragma unroll
  for (int g = 0; g < 3; ++g) {
    bih_r[g] = bihp[g * 1024 + jcol];
    bhh_r[g] = bhhp[g * 1024 + jcol];
  }

  float hprev[4] = {0.f, 0.f, 0.f, 0.f};
  float hacc[4]  = {0.f, 0.f, 0.f, 0.f};
  const int xorm = (bl & 7) << 4;
  const char* lbase = (const char*)h_lds + bl * 2048;

  // gx prefetch for step 0 (wave 0 = combiner)
  short gxr_[4][3];
  if (wave == 0) {
    #pragma unroll
    for (int r = 0; r < 4; ++r) {
      size_t base = ((size_t)(bteam + bsub + r) * SEQ + 0) * G3 + jcol;
      gxr_[r][0] = gx[base];
      gxr_[r][1] = gx[base + 1024];
      gxr_[r][2] = gx[base + 2048];
    }
  }

  #pragma unroll 1
  for (int s = 0; s < SEQ; ++s) {
    // parity regions: 6144 qwords/team, 24576/parity
    const ull* hsrc = hbuf_q + ((s & 1) ? 24576 : 0) + team * 6144;
    ull*       hdst = hbuf_q + (((s + 1) & 1) ? 24576 : 0) + team * 6144;

    // 1. stage MY K-quarter: epoch-validated packed loads (loads ARE the poll)
    {
      ull w[4][6];
      // initial batched issue: 24 loads
      #pragma unroll
      for (int p = 0; p < 4; ++p) {
        int P   = p * 64 + lane;
        int cgq = wave * 16 + (P >> 4);
        int b   = P & 15;
        const ull* q = hsrc + cgq * 96 + b * 6;
        #pragma unroll
        for (int j = 0; j < 6; ++j)
          w[p][j] = __hip_atomic_load(q + j, __ATOMIC_RELAXED,
                                      __HIP_MEMORY_SCOPE_AGENT);
      }
      // batched re-validation sweeps (per-lane; exec mask handles divergence)
      const ull want = (ull)(unsigned)s;
      for (;;) {
        int bad = 0;
        #pragma unroll
        for (int p = 0; p < 4; ++p) {
          int P   = p * 64 + lane;
          int cgq = wave * 16 + (P >> 4);
          int b   = P & 15;
          const ull* q = hsrc + cgq * 96 + b * 6;
          #pragma unroll
          for (int j = 0; j < 6; ++j)
            if ((w[p][j] >> 48) != want) {
              w[p][j] = __hip_atomic_load(q + j, __ATOMIC_RELAXED,
                                          __HIP_MEMORY_SCOPE_AGENT);
              bad = 1;
            }
        }
        if (!bad) break;
      }
      // unpack: per (cg,b) pair, 16 shorts from 6 qwords -> 4 swizzled ds_write_b64
      #pragma unroll
      for (int p = 0; p < 4; ++p) {
        int P   = p * 64 + lane;
        int cgq = wave * 16 + (P >> 4);
        int b   = P & 15;
        char* rowb = (char*)h_lds + b * 2048;
        int swz = (b & 7) << 4;
        #pragma unroll
        for (int c4 = 0; c4 < 4; ++c4) {
          ull u = 0;
          #pragma unroll
          for (int t = 0; t < 4; ++t) {
            int c = c4 * 4 + t;
            ull sh = (w[p][c / 3] >> ((c % 3) * 16)) & 0xFFFFull;
            u |= sh << (t * 16);
          }
          *(ull*)(rowb + ((cgq * 32 + c4 * 8) ^ swz)) = u;
        }
      }
    }

    // 2. partial gh over this wave's K-quarter: 24 MFMAs (own LDS region only)
    f32x4 a0 = {0.f,0.f,0.f,0.f}, a1 = {0.f,0.f,0.f,0.f}, a2 = {0.f,0.f,0.f,0.f};
    #pragma unroll
    for (int ks = 0; ks < 8; ++ks) {
      int k2 = wave * 512 + ks * 64 + (lane >> 4) * 16;   // byte offset of k*2
      bfrag af = *(const bfrag*)(lbase + (k2 ^ xorm));
      a0 = __builtin_amdgcn_mfma_f32_16x16x32_bf16(af, wfrag[0][ks], a0, 0, 0, 0);
      a1 = __builtin_amdgcn_mfma_f32_16x16x32_bf16(af, wfrag[1][ks], a1, 0, 0, 0);
      a2 = __builtin_amdgcn_mfma_f32_16x16x32_bf16(af, wfrag[2][ks], a2, 0, 0, 0);
    }
    if (wave) {
      int w1 = wave - 1;
      *(f32x4*)&part[((0 * 3 + w1) * 64 + lane) * 4] = a0;
      *(f32x4*)&part[((1 * 3 + w1) * 64 + lane) * 4] = a1;
      *(f32x4*)&part[((2 * 3 + w1) * 64 + lane) * 4] = a2;
    }
    __syncthreads();   // S2: partials ready

    // 3. wave 0: combine K-quarters, gates (fp32), stage h_new in LDS
    if (wave == 0) {
      f32x4 s0 = a0, s1 = a1, s2 = a2;
      #pragma unroll
      for (int w1 = 0; w1 < 3; ++w1) {
        s0 += *(const f32x4*)&part[((0 * 3 + w1) * 64 + lane) * 4];
        s1 += *(const f32x4*)&part[((1 * 3 + w1) * 64 + lane) * 4];
        s2 += *(const f32x4*)&part[((2 * 3 + w1) * 64 + lane) * 4];
      }
      #pragma unroll
      for (int r = 0; r < 4; ++r) {
        float ghr = s0[r] + bhh_r[0];
        float ghz = s1[r] + bhh_r[1];
        float ghn = s2[r] + bhh_r[2];
        float rg = fsig(bf2f(gxr_[r][0]) + bih_r[0] + ghr);
        float zg = fsig(bf2f(gxr_[r][1]) + bih_r[1] + ghz);
        float ng = ftanh(bf2f(gxr_[r][2]) + bih_r[2] + rg * ghn);
        float hn = (1.f - zg) * ng + zg * hprev[r];
        hprev[r] = hn;
        hacc[r] += hn;
        hstg[(bsub + r) * 16 + bl] = (short)f2bf(hn);   // exchange order [b][c]
      }
    }
    __syncthreads();   // S3: hstg ready

    // 4. wave 1: pack 96 epoch-tagged qwords and fire stores. NO drain, NO flag.
    if (wave == 1) {
      ull epv = (ull)(unsigned)(s + 1) << 48;
      #pragma unroll
      for (int rnd = 0; rnd < 2; ++rnd) {
        int q = rnd * 64 + lane;              // 0..127, valid < 96
        if (q < 96) {
          int b  = q / 6;
          int j  = q - b * 6;
          int c0 = 3 * j;
          ull v0 = (ull)(unsigned short)hstg[b * 16 + c0];
          ull v1 = (c0 + 1 < 16) ? (ull)(unsigned short)hstg[b * 16 + c0 + 1] : 0ull;
          ull v2 = (c0 + 2 < 16) ? (ull)(unsigned short)hstg[b * 16 + c0 + 2] : 0ull;
          ull pq = v0 | (v1 << 16) | (v2 << 32) | epv;
          __hip_atomic_store(hdst + cg * 96 + q, pq, __ATOMIC_RELAXED,
                             __HIP_MEMORY_SCOPE_AGENT);
        }
      }
    }
    // wave 0: prefetch next step's gx (in flight across next staging)
    if (wave == 0) {
      int sn = (s + 1 < SEQ) ? (s + 1) : s;
      #pragma unroll
      for (int r = 0; r < 4; ++r) {
        size_t base = ((size_t)(bteam + bsub + r) * SEQ + sn) * G3 + jcol;
        gxr_[r][0] = gx[base];
        gxr_[r][1] = gx[base + 1024];
        gxr_[r][2] = gx[base + 2048];
      }
    }
    // no S4: next iteration's epoch validation gates everything.
  }

  if (wave == 0) {
    #pragma unroll
    for (int r = 0; r < 4; ++r)
      hsum[(size_t)(bteam + bsub + r) * 1024 + jcol] = hacc[r] * (1.0f / 512.0f);
  }
}

// ---------- kernel 3: mean/logv projections (fp32) ----------
__global__ void proj_kernel(const float* __restrict__ hbar,
                            const float* __restrict__ wm, const float* __restrict__ bm,
                            const float* __restrict__ wl, const float* __restrict__ bl,
                            float* __restrict__ out)
{
  int b = blockIdx.x, t = threadIdx.x;  // 128 threads: 0-63 mean, 64-127 logv
  __shared__ float hrow[1024];
  for (int k = t; k < 1024; k += 128) hrow[k] = hbar[(size_t)b * 1024 + k];
  __syncthreads();
  int j = t & 63;
  const float* w = (t < 64) ? (wm + (size_t)j * 1024) : (wl + (size_t)j * 1024);
  float acc = (t < 64) ? bm[j] : bl[j];
  for (int k = 0; k < 1024; k += 4) {
    f32x4 wv = *(const f32x4*)(w + k);
    acc += hrow[k] * wv[0] + hrow[k+1] * wv[1] + hrow[k+2] * wv[2] + hrow[k+3] * wv[3];
  }
  out[(size_t)((t < 64) ? 0 : 4096) + b * 64 + j] = acc;
}

// ---------- launch ----------
extern "C" void kernel_launch(void* const* d_in, const int* in_sizes, int n_in,
                              void* d_out, int out_size, void* d_ws, size_t ws_size,
                              hipStream_t stream) {
  const int*   ids   = (const int*)d_in[0];
  const float* emb   = (const float*)d_in[1];
  const float* w_ih  = (const float*)d_in[2];
  const float* w_hh  = (const float*)d_in[3];
  const float* b_ih  = (const float*)d_in[4];
  const float* b_hh  = (const float*)d_in[5];
  const float* w_mean= (const float*)d_in[6];
  const float* b_mean= (const float*)d_in[7];
  const float* w_logv= (const float*)d_in[8];
  const float* b_logv= (const float*)d_in[9];
  float* out = (float*)d_out;

  char* ws = (char*)d_ws;
  // ws layout
  ull* hbuf_q   = (ull*)(ws);                      //    393216 B [2][4][64][96] epoch-tagged qwords
  float* hsum   = (float*)(ws + 393216);           //    262144 B [64][1024] f32
  short* wihb   = (short*)(ws + 393216 + 262144);              //   3145728 B
  short* gxbuf  = (short*)(ws + 393216 + 262144 + 3145728);    // 201326592 B

  // zero h exchange buffers -> epoch 0 == h(0) (deterministic across replays)
  hipMemsetAsync(ws, 0, 393216, stream);

  // 0: w_ih -> bf16
  cvt_wih_kernel<<<768, 256, 0, stream>>>(w_ih, wihb);
  // 1: gx GEMM
  gemm_gx_kernel<<<dim3(24, 256), 256, 0, stream>>>(ids, emb, wihb, gxbuf);
  // 2: persistent scan — 256 WGs x 256 thr, r14 skeleton with epoch-in-data
  //    exchange (no flags, no drains). All WGs co-resident.
  gru_scan_kernel<<<256, 256, 0, stream>>>(gxbuf, w_hh, b_ih, b_hh, hbuf_q, hsum);
  // 3: projections
  proj_kernel<<<64, 128, 0, stream>>>(hsum, w_mean, b_mean, w_logv, b_logv, out);
}

// Round 17
// 1927.978 us; speedup vs baseline: 2.3403x; 2.3403x over previous
//
#include <hip/hip_runtime.h>
#include <hip/hip_bf16.h>
#include <stdint.h>
#include <stddef.h>

// Problem sizes (fixed)
#define HID   1024
#define NB    64
#define SEQ   512
#define G3    3072   // 3*HID
#define EMB   512
#define LAT   64

typedef __attribute__((ext_vector_type(4))) float f32x4;
typedef __attribute__((ext_vector_type(8))) short bfrag;  // 8 bf16 (4 VGPRs)
typedef unsigned long long ull;

// ---------- helpers ----------
__device__ __forceinline__ unsigned short f2bf(float x) {   // RNE f32->bf16
  union { float f; unsigned u; } v; v.f = x;
  unsigned u = v.u + 0x7fffu + ((v.u >> 16) & 1u);
  return (unsigned short)(u >> 16);
}
__device__ __forceinline__ float bf2f(short s) {
  union { unsigned u; float f; } v; v.u = ((unsigned)(unsigned short)s) << 16;
  return v.f;
}
__device__ __forceinline__ float fsig(float x) {
  return 1.0f / (1.0f + __builtin_exp2f(-1.4426950408889634f * x));
}
__device__ __forceinline__ float ftanh(float x) {
  return 1.0f - 2.0f / (1.0f + __builtin_exp2f(2.8853900817779268f * x));
}
__device__ __forceinline__ void gload_lds16(const void* g, void* l) {
  __builtin_amdgcn_global_load_lds(
      (const __attribute__((address_space(1))) unsigned int*)g,
      (__attribute__((address_space(3))) unsigned int*)l, 16, 0, 0);
}

// ---------- kernel 0: w_ih f32 -> bf16 ----------
__global__ void cvt_wih_kernel(const float* __restrict__ in, short* __restrict__ out) {
  int i = (blockIdx.x * 256 + threadIdx.x) * 8;   // grid sized exactly
  f32x4 a = *(const f32x4*)(in + i);
  f32x4 b = *(const f32x4*)(in + i + 4);
  bfrag o;
  o[0]=(short)f2bf(a[0]); o[1]=(short)f2bf(a[1]); o[2]=(short)f2bf(a[2]); o[3]=(short)f2bf(a[3]);
  o[4]=(short)f2bf(b[0]); o[5]=(short)f2bf(b[1]); o[6]=(short)f2bf(b[2]); o[7]=(short)f2bf(b[3]);
  *(bfrag*)(out + i) = o;
}

// ---------- kernel 1: gx = emb[ids] @ w_ih^T  (bf16 MFMA, fp32 acc, bf16 out) ----------
__global__ void __launch_bounds__(256) gemm_gx_kernel(
    const int* __restrict__ ids, const float* __restrict__ emb,
    const short* __restrict__ wih, short* __restrict__ gx)
{
  const int nt = blockIdx.x, mt = blockIdx.y;
  const int tid = threadIdx.x;
  const int lane = tid & 63, wave = tid >> 6;
  const int wr = wave >> 1, wc = wave & 1;

  __shared__ __align__(16) short A_lds[128 * 48];
  __shared__ __align__(16) short B_lds[128 * 32];
  __shared__ int ids_s[128];

  if (tid < 128) ids_s[tid] = ids[mt * 128 + tid];
  __syncthreads();

  f32x4 acc[4][4];
  #pragma unroll
  for (int i = 0; i < 4; ++i)
    #pragma unroll
    for (int j = 0; j < 4; ++j) acc[i][j] = (f32x4){0.f, 0.f, 0.f, 0.f};

  const int r_stage = tid >> 1;
  const int kh = (tid & 1) * 16;

  #pragma unroll 1
  for (int kc = 0; kc < 16; ++kc) {
    __syncthreads();
    {
      const float* src = emb + (size_t)ids_s[r_stage] * 512 + kc * 32 + kh;
      f32x4 v0 = *(const f32x4*)(src);
      f32x4 v1 = *(const f32x4*)(src + 4);
      f32x4 v2 = *(const f32x4*)(src + 8);
      f32x4 v3 = *(const f32x4*)(src + 12);
      bfrag p0, p1;
      p0[0]=(short)f2bf(v0[0]); p0[1]=(short)f2bf(v0[1]); p0[2]=(short)f2bf(v0[2]); p0[3]=(short)f2bf(v0[3]);
      p0[4]=(short)f2bf(v1[0]); p0[5]=(short)f2bf(v1[1]); p0[6]=(short)f2bf(v1[2]); p0[7]=(short)f2bf(v1[3]);
      p1[0]=(short)f2bf(v2[0]); p1[1]=(short)f2bf(v2[1]); p1[2]=(short)f2bf(v2[2]); p1[3]=(short)f2bf(v2[3]);
      p1[4]=(short)f2bf(v3[0]); p1[5]=(short)f2bf(v3[1]); p1[6]=(short)f2bf(v3[2]); p1[7]=(short)f2bf(v3[3]);
      *(bfrag*)&A_lds[r_stage * 48 + kh]     = p0;
      *(bfrag*)&A_lds[r_stage * 48 + kh + 8] = p1;
    }
    {
      #pragma unroll
      for (int ii = 0; ii < 2; ++ii) {
        int i = wave * 2 + ii;
        const short* src = wih + (size_t)(nt * 128 + i * 16 + (lane >> 2)) * 512
                               + kc * 32 + (lane & 3) * 8;
        gload_lds16((const void*)src, (void*)&B_lds[i * 512]);
      }
    }
    asm volatile("s_waitcnt vmcnt(0)" ::: "memory");
    __syncthreads();

    bfrag a[4], b[4];
    #pragma unroll
    for (int mi = 0; mi < 4; ++mi)
      a[mi] = *(const bfrag*)&A_lds[(wr * 64 + mi * 16 + (lane & 15)) * 48 + (lane >> 4) * 8];
    #pragma unroll
    for (int ni = 0; ni < 4; ++ni)
      b[ni] = *(const bfrag*)&B_lds[(wc * 64 + ni * 16 + (lane & 15)) * 32 + (lane >> 4) * 8];
    #pragma unroll
    for (int mi = 0; mi < 4; ++mi)
      #pragma unroll
      for (int ni = 0; ni < 4; ++ni)
        acc[mi][ni] = __builtin_amdgcn_mfma_f32_16x16x32_bf16(a[mi], b[ni], acc[mi][ni], 0, 0, 0);
  }

  #pragma unroll
  for (int mi = 0; mi < 4; ++mi)
    #pragma unroll
    for (int ni = 0; ni < 4; ++ni)
      #pragma unroll
      for (int r = 0; r < 4; ++r) {
        int m = mt * 128 + wr * 64 + mi * 16 + (lane >> 4) * 4 + r;
        int n = nt * 128 + wc * 64 + ni * 16 + (lane & 15);
        gx[(size_t)m * G3 + n] = (short)f2bf(acc[mi][ni][r]);
      }
}

// ---------- kernel 2: persistent GRU scan — r14 protocol, wave0-publish, no S3 ----------
// 256 WGs x 256 thr (4 waves). WG = (team = bid>>6 owns 16 batch rows,
// cg = bid&63 owns 16 hidden cols). Wave = K-quarter (wfrag[3][8] = 96 VGPRs).
// Per step: per-wave poll (own quarter's 16 writer flags) -> stage own quarter
// -> 24 MFMAs -> partials to PARITY-buffered part[] -> S2 -> wave0: combine +
// gates + hstg (wave0-PRIVATE: its 64 lanes write all 256 entries) ->
// lgkmcnt(0) -> qword read -> ONE 512B burst -> drain -> flag -> gx prefetch.
// No S3, no cross-wave handoff. Waves 1-3 run ahead into next poll.
// Hazards: part parity closes the fast-wave3-vs-slow-wave0 window; hstg is
// wave0-private (program order + lgkmcnt); h double-buffer WAR by transitivity
// (staging h(s) requires flags(s) which require writers' staging of h(s-1));
// polls acyclic (flags monotone).
__global__ void __launch_bounds__(256, 1) gru_scan_kernel(
    const short* __restrict__ gx, const float* __restrict__ whh,
    const float* __restrict__ bihp, const float* __restrict__ bhhp,
    ull* __restrict__ hbuf_q, unsigned int* __restrict__ flags,
    float* __restrict__ hsum)
{
  const int wg   = blockIdx.x;       // 0..255
  const int team = wg >> 6;          // 0..3
  const int cg   = wg & 63;          // col-group
  const int tid  = threadIdx.x;
  const int lane = tid & 63, wave = tid >> 6;   // wave = K-quarter 0..3
  const int bl   = lane & 15;
  const int bsub = (lane >> 4) * 4;
  const int jcol = cg * 16 + bl;
  const int bteam = team * 16;

  __shared__ __align__(16) short h_lds[16 * 1024];     // 32 KB [b][k] swizzled
  __shared__ __align__(16) float part[2 * 3 * 3 * 256];// 18 KB [par][g][wave-1][lane*4]
  __shared__ __align__(16) short hstg[256];            // 512 B wave0-PRIVATE scratch

  // --- weights: 16 cols x 3 gates x K-quarter as B-frags (bf16), 96 VGPRs ---
  bfrag wfrag[3][8];
  #pragma unroll
  for (int g = 0; g < 3; ++g) {
    const float* wrow = whh + (size_t)(g * 1024 + jcol) * 1024 + wave * 256 + (lane >> 4) * 8;
    #pragma unroll
    for (int ks = 0; ks < 8; ++ks) {
      const float* p = wrow + ks * 32;
      f32x4 lo = *(const f32x4*)p;
      f32x4 hi = *(const f32x4*)(p + 4);
      bfrag f;
      f[0]=(short)f2bf(lo[0]); f[1]=(short)f2bf(lo[1]); f[2]=(short)f2bf(lo[2]); f[3]=(short)f2bf(lo[3]);
      f[4]=(short)f2bf(hi[0]); f[5]=(short)f2bf(hi[1]); f[6]=(short)f2bf(hi[2]); f[7]=(short)f2bf(hi[3]);
      wfrag[g][ks] = f;
    }
  }
  float bih_r[3], bhh_r[3];
  #pragma unroll
  for (int g = 0; g < 3; ++g) {
    bih_r[g] = bihp[g * 1024 + jcol];
    bhh_r[g] = bhhp[g * 1024 + jcol];
  }

  float hprev[4] = {0.f, 0.f, 0.f, 0.f};
  float hacc[4]  = {0.f, 0.f, 0.f, 0.f};
  const int xorm = (bl & 7) << 4;
  const char* lbase = (const char*)h_lds + bl * 2048;
  unsigned int* fteam  = flags + team * 1024;     // 64 flags, 64B (16 u32) apart
  unsigned int* myflag = fteam + cg * 16;
  unsigned int* fq     = fteam + (wave * 16 + (lane & 15)) * 16;  // my quarter's 16 flags

  // wave-private staging constants (wave stages qwords q = wave*1024 + j*64 + lane)
  const int st_c4 = lane & 3;
  char* const st_base = (char*)h_lds + (lane >> 2) * 2048;
  const int st_swz = ((lane >> 2) & 7) << 4;

  // gx prefetch for step 0 (wave 0 = combiner)
  short gxr_[4][3];
  if (wave == 0) {
    #pragma unroll
    for (int r = 0; r < 4; ++r) {
      size_t base = ((size_t)(bteam + bsub + r) * SEQ + 0) * G3 + jcol;
      gxr_[r][0] = gx[base];
      gxr_[r][1] = gx[base + 1024];
      gxr_[r][2] = gx[base + 2048];
    }
  }

  #pragma unroll 1
  for (int s = 0; s < SEQ; ++s) {
    const ull* hsrc = hbuf_q + ((s & 1) ? 16384 : 0) + team * 4096;       // 4096 qwords
    ull*       hdst = hbuf_q + (((s + 1) & 1) ? 16384 : 0) + team * 4096;
    const int  par  = (s & 1) * 9;   // part[] parity row base

    // 1. per-wave poll: my quarter's 16 writer flags >= s (s=0 trivially true)
    {
      unsigned tgt = (unsigned)s;
      for (;;) {
        unsigned v = __hip_atomic_load(fq, __ATOMIC_RELAXED, __HIP_MEMORY_SCOPE_AGENT);
        if (__all((int)(v >= tgt))) break;
      }
    }

    // 2. stage MY K-quarter -> my LDS region (16 coalesced agent 8B loads)
    {
      ull hv[16];
      #pragma unroll
      for (int j = 0; j < 16; ++j)
        hv[j] = __hip_atomic_load(hsrc + wave * 1024 + j * 64 + lane,
                                  __ATOMIC_RELAXED, __HIP_MEMORY_SCOPE_AGENT);
      #pragma unroll
      for (int j = 0; j < 16; ++j) {
        int cgq = wave * 16 + j;
        *(ull*)(st_base + ((cgq * 32 + st_c4 * 8) ^ st_swz)) = hv[j];
      }
    }

    // 3. partial gh over this wave's K-quarter: 24 MFMAs (own LDS region only)
    f32x4 a0 = {0.f,0.f,0.f,0.f}, a1 = {0.f,0.f,0.f,0.f}, a2 = {0.f,0.f,0.f,0.f};
    #pragma unroll
    for (int ks = 0; ks < 8; ++ks) {
      int k2 = wave * 512 + ks * 64 + (lane >> 4) * 16;   // byte offset of k*2
      bfrag af = *(const bfrag*)(lbase + (k2 ^ xorm));
      a0 = __builtin_amdgcn_mfma_f32_16x16x32_bf16(af, wfrag[0][ks], a0, 0, 0, 0);
      a1 = __builtin_amdgcn_mfma_f32_16x16x32_bf16(af, wfrag[1][ks], a1, 0, 0, 0);
      a2 = __builtin_amdgcn_mfma_f32_16x16x32_bf16(af, wfrag[2][ks], a2, 0, 0, 0);
    }
    if (wave) {
      int w1 = wave - 1;
      *(f32x4*)&part[((par + 0 * 3 + w1) * 64 + lane) * 4] = a0;
      *(f32x4*)&part[((par + 1 * 3 + w1) * 64 + lane) * 4] = a1;
      *(f32x4*)&part[((par + 2 * 3 + w1) * 64 + lane) * 4] = a2;
    }
    __syncthreads();   // S2: partials ready (the only barrier per step)

    // 4. wave 0: combine, gates, wave-private hstg transpose, publish, flag
    if (wave == 0) {
      f32x4 s0 = a0, s1 = a1, s2 = a2;
      #pragma unroll
      for (int w1 = 0; w1 < 3; ++w1) {
        s0 += *(const f32x4*)&part[((par + 0 * 3 + w1) * 64 + lane) * 4];
        s1 += *(const f32x4*)&part[((par + 1 * 3 + w1) * 64 + lane) * 4];
        s2 += *(const f32x4*)&part[((par + 2 * 3 + w1) * 64 + lane) * 4];
      }
      #pragma unroll
      for (int r = 0; r < 4; ++r) {
        float ghr = s0[r] + bhh_r[0];
        float ghz = s1[r] + bhh_r[1];
        float ghn = s2[r] + bhh_r[2];
        float rg = fsig(bf2f(gxr_[r][0]) + bih_r[0] + ghr);
        float zg = fsig(bf2f(gxr_[r][1]) + bih_r[1] + ghz);
        float ng = ftanh(bf2f(gxr_[r][2]) + bih_r[2] + rg * ghn);
        float hn = (1.f - zg) * ng + zg * hprev[r];
        hprev[r] = hn;
        hacc[r] += hn;
        hstg[(bsub + r) * 16 + bl] = (short)f2bf(hn);   // exchange order [b][c]
      }
      // wave-private transpose readback: wave0 wrote ALL 256 entries itself
      asm volatile("s_waitcnt lgkmcnt(0)" ::: "memory");
      __builtin_amdgcn_sched_barrier(0);
      ull v = ((const ull*)hstg)[lane];
      __hip_atomic_store(hdst + cg * 64 + lane, v, __ATOMIC_RELAXED,
                         __HIP_MEMORY_SCOPE_AGENT);
      asm volatile("s_waitcnt vmcnt(0)" ::: "memory");   // publish drained
      if (lane == 0)
        __hip_atomic_store(myflag, (unsigned)(s + 1), __ATOMIC_RELAXED,
                           __HIP_MEMORY_SCOPE_AGENT);
      // prefetch next step's gx (rides under the next poll)
      int sn = (s + 1 < SEQ) ? (s + 1) : s;
      #pragma unroll
      for (int r = 0; r < 4; ++r) {
        size_t base = ((size_t)(bteam + bsub + r) * SEQ + sn) * G3 + jcol;
        gxr_[r][0] = gx[base];
        gxr_[r][1] = gx[base + 1024];
        gxr_[r][2] = gx[base + 2048];
      }
    }
    // waves 1-3: fall straight through to next step's poll (run-ahead)
  }

  if (wave == 0) {
    #pragma unroll
    for (int r = 0; r < 4; ++r)
      hsum[(size_t)(bteam + bsub + r) * 1024 + jcol] = hacc[r] * (1.0f / 512.0f);
  }
}

// ---------- kernel 3: mean/logv projections (fp32) ----------
__global__ void proj_kernel(const float* __restrict__ hbar,
                            const float* __restrict__ wm, const float* __restrict__ bm,
                            const float* __restrict__ wl, const float* __restrict__ bl,
                            float* __restrict__ out)
{
  int b = blockIdx.x, t = threadIdx.x;  // 128 threads: 0-63 mean, 64-127 logv
  __shared__ float hrow[1024];
  for (int k = t; k < 1024; k += 128) hrow[k] = hbar[(size_t)b * 1024 + k];
  __syncthreads();
  int j = t & 63;
  const float* w = (t < 64) ? (wm + (size_t)j * 1024) : (wl + (size_t)j * 1024);
  float acc = (t < 64) ? bm[j] : bl[j];
  for (int k = 0; k < 1024; k += 4) {
    f32x4 wv = *(const f32x4*)(w + k);
    acc += hrow[k] * wv[0] + hrow[k+1] * wv[1] + hrow[k+2] * wv[2] + hrow[k+3] * wv[3];
  }
  out[(size_t)((t < 64) ? 0 : 4096) + b * 64 + j] = acc;
}

// ---------- launch ----------
extern "C" void kernel_launch(void* const* d_in, const int* in_sizes, int n_in,
                              void* d_out, int out_size, void* d_ws, size_t ws_size,
                              hipStream_t stream) {
  const int*   ids   = (const int*)d_in[0];
  const float* emb   = (const float*)d_in[1];
  const float* w_ih  = (const float*)d_in[2];
  const float* w_hh  = (const float*)d_in[3];
  const float* b_ih  = (const float*)d_in[4];
  const float* b_hh  = (const float*)d_in[5];
  const float* w_mean= (const float*)d_in[6];
  const float* b_mean= (const float*)d_in[7];
  const float* w_logv= (const float*)d_in[8];
  const float* b_logv= (const float*)d_in[9];
  float* out = (float*)d_out;

  char* ws = (char*)d_ws;
  // ws layout
  unsigned int* flags = (unsigned int*)(ws);                 //     16384 B (4 teams x 64 flags, 64B apart)
  ull* hbuf_q        = (ull*)(ws + 16384);                   //    262144 B [2][4][4096] qwords bf16 ([cg][b][c4])
  float* hsum        = (float*)(ws + 16384 + 262144);        //    262144 B [64][1024] f32
  short* wihb        = (short*)(ws + 16384 + 262144 + 262144);           //   3145728 B
  short* gxbuf       = (short*)(ws + 16384 + 262144 + 262144 + 3145728); // 201326592 B

  // zero flags + h double-buffers (deterministic across graph replays)
  hipMemsetAsync(ws, 0, 16384 + 262144, stream);

  // 0: w_ih -> bf16
  cvt_wih_kernel<<<768, 256, 0, stream>>>(w_ih, wihb);
  // 1: gx GEMM
  gemm_gx_kernel<<<dim3(24, 256), 256, 0, stream>>>(ids, emb, wihb, gxbuf);
  // 2: persistent scan — 256 WGs x 256 thr, 1-barrier protocol (wave0 publishes
  //    via wave-private hstg; parity-buffered partials). All WGs co-resident.
  gru_scan_kernel<<<256, 256, 0, stream>>>(gxbuf, w_hh, b_ih, b_hh, hbuf_q, flags, hsum);
  // 3: projections
  proj_kernel<<<64, 128, 0, stream>>>(hsum, w_mean, b_mean, w_logv, b_logv, out);
}

// Round 18
// 1845.226 us; speedup vs baseline: 2.4453x; 1.0448x over previous
//
#include <hip/hip_runtime.h>
#include <hip/hip_bf16.h>
#include <stdint.h>
#include <stddef.h>

// Problem sizes (fixed)
#define HID   1024
#define NB    64
#define SEQ   512
#define G3    3072   // 3*HID
#define EMB   512
#define LAT   64
#define VOCAB 32000

typedef __attribute__((ext_vector_type(4))) float f32x4;
typedef __attribute__((ext_vector_type(8))) short bfrag;  // 8 bf16 (4 VGPRs)
typedef unsigned long long ull;

// ---------- helpers ----------
__device__ __forceinline__ unsigned short f2bf(float x) {   // RNE f32->bf16
  union { float f; unsigned u; } v; v.f = x;
  unsigned u = v.u + 0x7fffu + ((v.u >> 16) & 1u);
  return (unsigned short)(u >> 16);
}
__device__ __forceinline__ float bf2f(short s) {
  union { unsigned u; float f; } v; v.u = ((unsigned)(unsigned short)s) << 16;
  return v.f;
}
__device__ __forceinline__ float fsig(float x) {
  return 1.0f / (1.0f + __builtin_exp2f(-1.4426950408889634f * x));
}
__device__ __forceinline__ float ftanh(float x) {
  return 1.0f - 2.0f / (1.0f + __builtin_exp2f(2.8853900817779268f * x));
}
__device__ __forceinline__ void gload_lds16(const void* g, void* l) {
  __builtin_amdgcn_global_load_lds(
      (const __attribute__((address_space(1))) unsigned int*)g,
      (__attribute__((address_space(3))) unsigned int*)l, 16, 0, 0);
}

// ---------- kernel 0a: f32 -> bf16 bulk convert (w_ih / emb) ----------
__global__ void cvt_bf16_kernel(const float* __restrict__ in, short* __restrict__ out) {
  int i = (blockIdx.x * 256 + threadIdx.x) * 8;   // grid sized exactly
  f32x4 a = *(const f32x4*)(in + i);
  f32x4 b = *(const f32x4*)(in + i + 4);
  bfrag o;
  o[0]=(short)f2bf(a[0]); o[1]=(short)f2bf(a[1]); o[2]=(short)f2bf(a[2]); o[3]=(short)f2bf(a[3]);
  o[4]=(short)f2bf(b[0]); o[5]=(short)f2bf(b[1]); o[6]=(short)f2bf(b[2]); o[7]=(short)f2bf(b[3]);
  *(bfrag*)(out + i) = o;
}

// ---------- kernel 1: gx = emb[ids] @ w_ih^T  (bf16 MFMA, fp32 acc, bf16 out) ----------
// A-path: PRE-CONVERTED bf16 emb -> 2 vector loads + 2 ds_writes per thread per
// K-chunk (no f2bf VALU in the hot loop, half the A-tile global bytes).
__global__ void __launch_bounds__(256) gemm_gx_kernel(
    const int* __restrict__ ids, const short* __restrict__ embb,
    const short* __restrict__ wih, short* __restrict__ gx)
{
  const int nt = blockIdx.x, mt = blockIdx.y;
  const int tid = threadIdx.x;
  const int lane = tid & 63, wave = tid >> 6;
  const int wr = wave >> 1, wc = wave & 1;

  __shared__ __align__(16) short A_lds[128 * 48];
  __shared__ __align__(16) short B_lds[128 * 32];
  __shared__ int ids_s[128];

  if (tid < 128) ids_s[tid] = ids[mt * 128 + tid];
  __syncthreads();

  f32x4 acc[4][4];
  #pragma unroll
  for (int i = 0; i < 4; ++i)
    #pragma unroll
    for (int j = 0; j < 4; ++j) acc[i][j] = (f32x4){0.f, 0.f, 0.f, 0.f};

  const int r_stage = tid >> 1;
  const int kh = (tid & 1) * 16;

  #pragma unroll 1
  for (int kc = 0; kc < 16; ++kc) {
    __syncthreads();
    // A stage: gathered bf16 row chunk, no conversion
    {
      const short* src = embb + (size_t)ids_s[r_stage] * 512 + kc * 32 + kh;
      bfrag p0 = *(const bfrag*)(src);
      bfrag p1 = *(const bfrag*)(src + 8);
      *(bfrag*)&A_lds[r_stage * 48 + kh]     = p0;
      *(bfrag*)&A_lds[r_stage * 48 + kh + 8] = p1;
    }
    // B stage: direct global->LDS
    {
      #pragma unroll
      for (int ii = 0; ii < 2; ++ii) {
        int i = wave * 2 + ii;
        const short* src = wih + (size_t)(nt * 128 + i * 16 + (lane >> 2)) * 512
                               + kc * 32 + (lane & 3) * 8;
        gload_lds16((const void*)src, (void*)&B_lds[i * 512]);
      }
    }
    asm volatile("s_waitcnt vmcnt(0)" ::: "memory");
    __syncthreads();

    bfrag a[4], b[4];
    #pragma unroll
    for (int mi = 0; mi < 4; ++mi)
      a[mi] = *(const bfrag*)&A_lds[(wr * 64 + mi * 16 + (lane & 15)) * 48 + (lane >> 4) * 8];
    #pragma unroll
    for (int ni = 0; ni < 4; ++ni)
      b[ni] = *(const bfrag*)&B_lds[(wc * 64 + ni * 16 + (lane & 15)) * 32 + (lane >> 4) * 8];
    #pragma unroll
    for (int mi = 0; mi < 4; ++mi)
      #pragma unroll
      for (int ni = 0; ni < 4; ++ni)
        acc[mi][ni] = __builtin_amdgcn_mfma_f32_16x16x32_bf16(a[mi], b[ni], acc[mi][ni], 0, 0, 0);
  }

  #pragma unroll
  for (int mi = 0; mi < 4; ++mi)
    #pragma unroll
    for (int ni = 0; ni < 4; ++ni)
      #pragma unroll
      for (int r = 0; r < 4; ++r) {
        int m = mt * 128 + wr * 64 + mi * 16 + (lane >> 4) * 4 + r;
        int n = nt * 128 + wc * 64 + ni * 16 + (lane & 15);
        gx[(size_t)m * G3 + n] = (short)f2bf(acc[mi][ni][r]);
      }
}

// ---------- kernel 1-fallback: f32-A variant (used only if ws too small) ----------
__global__ void __launch_bounds__(256) gemm_gx_f32a_kernel(
    const int* __restrict__ ids, const float* __restrict__ emb,
    const short* __restrict__ wih, short* __restrict__ gx)
{
  const int nt = blockIdx.x, mt = blockIdx.y;
  const int tid = threadIdx.x;
  const int lane = tid & 63, wave = tid >> 6;
  const int wr = wave >> 1, wc = wave & 1;

  __shared__ __align__(16) short A_lds[128 * 48];
  __shared__ __align__(16) short B_lds[128 * 32];
  __shared__ int ids_s[128];

  if (tid < 128) ids_s[tid] = ids[mt * 128 + tid];
  __syncthreads();

  f32x4 acc[4][4];
  #pragma unroll
  for (int i = 0; i < 4; ++i)
    #pragma unroll
    for (int j = 0; j < 4; ++j) acc[i][j] = (f32x4){0.f, 0.f, 0.f, 0.f};

  const int r_stage = tid >> 1;
  const int kh = (tid & 1) * 16;

  #pragma unroll 1
  for (int kc = 0; kc < 16; ++kc) {
    __syncthreads();
    {
      const float* src = emb + (size_t)ids_s[r_stage] * 512 + kc * 32 + kh;
      f32x4 v0 = *(const f32x4*)(src);
      f32x4 v1 = *(const f32x4*)(src + 4);
      f32x4 v2 = *(const f32x4*)(src + 8);
      f32x4 v3 = *(const f32x4*)(src + 12);
      bfrag p0, p1;
      p0[0]=(short)f2bf(v0[0]); p0[1]=(short)f2bf(v0[1]); p0[2]=(short)f2bf(v0[2]); p0[3]=(short)f2bf(v0[3]);
      p0[4]=(short)f2bf(v1[0]); p0[5]=(short)f2bf(v1[1]); p0[6]=(short)f2bf(v1[2]); p0[7]=(short)f2bf(v1[3]);
      p1[0]=(short)f2bf(v2[0]); p1[1]=(short)f2bf(v2[1]); p1[2]=(short)f2bf(v2[2]); p1[3]=(short)f2bf(v2[3]);
      p1[4]=(short)f2bf(v3[0]); p1[5]=(short)f2bf(v3[1]); p1[6]=(short)f2bf(v3[2]); p1[7]=(short)f2bf(v3[3]);
      *(bfrag*)&A_lds[r_stage * 48 + kh]     = p0;
      *(bfrag*)&A_lds[r_stage * 48 + kh + 8] = p1;
    }
    {
      #pragma unroll
      for (int ii = 0; ii < 2; ++ii) {
        int i = wave * 2 + ii;
        const short* src = wih + (size_t)(nt * 128 + i * 16 + (lane >> 2)) * 512
                               + kc * 32 + (lane & 3) * 8;
        gload_lds16((const void*)src, (void*)&B_lds[i * 512]);
      }
    }
    asm volatile("s_waitcnt vmcnt(0)" ::: "memory");
    __syncthreads();

    bfrag a[4], b[4];
    #pragma unroll
    for (int mi = 0; mi < 4; ++mi)
      a[mi] = *(const bfrag*)&A_lds[(wr * 64 + mi * 16 + (lane & 15)) * 48 + (lane >> 4) * 8];
    #pragma unroll
    for (int ni = 0; ni < 4; ++ni)
      b[ni] = *(const bfrag*)&B_lds[(wc * 64 + ni * 16 + (lane & 15)) * 32 + (lane >> 4) * 8];
    #pragma unroll
    for (int mi = 0; mi < 4; ++mi)
      #pragma unroll
      for (int ni = 0; ni < 4; ++ni)
        acc[mi][ni] = __builtin_amdgcn_mfma_f32_16x16x32_bf16(a[mi], b[ni], acc[mi][ni], 0, 0, 0);
  }

  #pragma unroll
  for (int mi = 0; mi < 4; ++mi)
    #pragma unroll
    for (int ni = 0; ni < 4; ++ni)
      #pragma unroll
      for (int r = 0; r < 4; ++r) {
        int m = mt * 128 + wr * 64 + mi * 16 + (lane >> 4) * 4 + r;
        int n = nt * 128 + wc * 64 + ni * 16 + (lane & 15);
        gx[(size_t)m * G3 + n] = (short)f2bf(acc[mi][ni][r]);
      }
}

// ---------- kernel 2: persistent GRU scan — r14 protocol (proven best) ----------
// 256 WGs x 256 thr (4 waves). WG = (team = bid>>6 owns 16 batch rows,
// cg = bid&63 owns 16 hidden cols). Wave = K-quarter (wfrag[3][8] = 96 VGPRs).
// Per step: per-wave poll (own quarter's 16 writer flags) -> stage own quarter
// -> 24 MFMAs -> partials -> S2 -> wave0 combine+gates+hstg -> S3 -> wave1
// publishes ONE 512B burst + drain + flag; wave0 prefetches gx. No S4.
__global__ void __launch_bounds__(256, 1) gru_scan_kernel(
    const short* __restrict__ gx, const float* __restrict__ whh,
    const float* __restrict__ bihp, const float* __restrict__ bhhp,
    ull* __restrict__ hbuf_q, unsigned int* __restrict__ flags,
    float* __restrict__ hsum)
{
  const int wg   = blockIdx.x;       // 0..255
  const int team = wg >> 6;          // 0..3
  const int cg   = wg & 63;          // col-group
  const int tid  = threadIdx.x;
  const int lane = tid & 63, wave = tid >> 6;   // wave = K-quarter 0..3
  const int bl   = lane & 15;
  const int bsub = (lane >> 4) * 4;
  const int jcol = cg * 16 + bl;
  const int bteam = team * 16;

  __shared__ __align__(16) short h_lds[16 * 1024];   // 32 KB [b][k] swizzled
  __shared__ __align__(16) float part[3 * 3 * 256];  // 9 KB [g][wave-1][lane*4]
  __shared__ __align__(16) short hstg[256];          // 512 B [b][c] exchange order

  // --- weights: 16 cols x 3 gates x K-quarter as B-frags (bf16), 96 VGPRs ---
  bfrag wfrag[3][8];
  #pragma unroll
  for (int g = 0; g < 3; ++g) {
    const float* wrow = whh + (size_t)(g * 1024 + jcol) * 1024 + wave * 256 + (lane >> 4) * 8;
    #pragma unroll
    for (int ks = 0; ks < 8; ++ks) {
      const float* p = wrow + ks * 32;
      f32x4 lo = *(const f32x4*)p;
      f32x4 hi = *(const f32x4*)(p + 4);
      bfrag f;
      f[0]=(short)f2bf(lo[0]); f[1]=(short)f2bf(lo[1]); f[2]=(short)f2bf(lo[2]); f[3]=(short)f2bf(lo[3]);
      f[4]=(short)f2bf(hi[0]); f[5]=(short)f2bf(hi[1]); f[6]=(short)f2bf(hi[2]); f[7]=(short)f2bf(hi[3]);
      wfrag[g][ks] = f;
    }
  }
  float bih_r[3], bhh_r[3];
  #pragma unroll
  for (int g = 0; g < 3; ++g) {
    bih_r[g] = bihp[g * 1024 + jcol];
    bhh_r[g] = bhhp[g * 1024 + jcol];
  }

  float hprev[4] = {0.f, 0.f, 0.f, 0.f};
  float hacc[4]  = {0.f, 0.f, 0.f, 0.f};
  const int xorm = (bl & 7) << 4;
  const char* lbase = (const char*)h_lds + bl * 2048;
  unsigned int* fteam  = flags + team * 1024;     // 64 flags, 64B (16 u32) apart
  unsigned int* myflag = fteam + cg * 16;
  unsigned int* fq     = fteam + (wave * 16 + (lane & 15)) * 16;  // my quarter's 16 flags

  // wave-private staging constants (wave stages qwords q = wave*1024 + j*64 + lane)
  const int st_c4 = lane & 3;
  char* const st_base = (char*)h_lds + (lane >> 2) * 2048;
  const int st_swz = ((lane >> 2) & 7) << 4;

  // gx prefetch for step 0 (wave 0 = combiner)
  short gxr_[4][3];
  if (wave == 0) {
    #pragma unroll
    for (int r = 0; r < 4; ++r) {
      size_t base = ((size_t)(bteam + bsub + r) * SEQ + 0) * G3 + jcol;
      gxr_[r][0] = gx[base];
      gxr_[r][1] = gx[base + 1024];
      gxr_[r][2] = gx[base + 2048];
    }
  }

  #pragma unroll 1
  for (int s = 0; s < SEQ; ++s) {
    const ull* hsrc = hbuf_q + ((s & 1) ? 16384 : 0) + team * 4096;       // 4096 qwords
    ull*       hdst = hbuf_q + (((s + 1) & 1) ? 16384 : 0) + team * 4096;

    // 1. per-wave poll: my quarter's 16 writer flags >= s (s=0 trivially true)
    {
      unsigned tgt = (unsigned)s;
      for (;;) {
        unsigned v = __hip_atomic_load(fq, __ATOMIC_RELAXED, __HIP_MEMORY_SCOPE_AGENT);
        if (__all((int)(v >= tgt))) break;
      }
    }

    // 2. stage MY K-quarter -> my LDS region (16 coalesced agent 8B loads)
    {
      ull hv[16];
      #pragma unroll
      for (int j = 0; j < 16; ++j)
        hv[j] = __hip_atomic_load(hsrc + wave * 1024 + j * 64 + lane,
                                  __ATOMIC_RELAXED, __HIP_MEMORY_SCOPE_AGENT);
      #pragma unroll
      for (int j = 0; j < 16; ++j) {
        int cgq = wave * 16 + j;
        *(ull*)(st_base + ((cgq * 32 + st_c4 * 8) ^ st_swz)) = hv[j];
      }
    }

    // 3. partial gh over this wave's K-quarter: 24 MFMAs (own LDS region only)
    f32x4 a0 = {0.f,0.f,0.f,0.f}, a1 = {0.f,0.f,0.f,0.f}, a2 = {0.f,0.f,0.f,0.f};
    #pragma unroll
    for (int ks = 0; ks < 8; ++ks) {
      int k2 = wave * 512 + ks * 64 + (lane >> 4) * 16;   // byte offset of k*2
      bfrag af = *(const bfrag*)(lbase + (k2 ^ xorm));
      a0 = __builtin_amdgcn_mfma_f32_16x16x32_bf16(af, wfrag[0][ks], a0, 0, 0, 0);
      a1 = __builtin_amdgcn_mfma_f32_16x16x32_bf16(af, wfrag[1][ks], a1, 0, 0, 0);
      a2 = __builtin_amdgcn_mfma_f32_16x16x32_bf16(af, wfrag[2][ks], a2, 0, 0, 0);
    }
    if (wave) {
      int w1 = wave - 1;
      *(f32x4*)&part[((0 * 3 + w1) * 64 + lane) * 4] = a0;
      *(f32x4*)&part[((1 * 3 + w1) * 64 + lane) * 4] = a1;
      *(f32x4*)&part[((2 * 3 + w1) * 64 + lane) * 4] = a2;
    }
    __syncthreads();   // S2: partials ready

    // 4. wave 0: combine K-quarters, gates (fp32), stage h_new in LDS
    if (wave == 0) {
      f32x4 s0 = a0, s1 = a1, s2 = a2;
      #pragma unroll
      for (int w1 = 0; w1 < 3; ++w1) {
        s0 += *(const f32x4*)&part[((0 * 3 + w1) * 64 + lane) * 4];
        s1 += *(const f32x4*)&part[((1 * 3 + w1) * 64 + lane) * 4];
        s2 += *(const f32x4*)&part[((2 * 3 + w1) * 64 + lane) * 4];
      }
      #pragma unroll
      for (int r = 0; r < 4; ++r) {
        float ghr = s0[r] + bhh_r[0];
        float ghz = s1[r] + bhh_r[1];
        float ghn = s2[r] + bhh_r[2];
        float rg = fsig(bf2f(gxr_[r][0]) + bih_r[0] + ghr);
        float zg = fsig(bf2f(gxr_[r][1]) + bih_r[1] + ghz);
        float ng = ftanh(bf2f(gxr_[r][2]) + bih_r[2] + rg * ghn);
        float hn = (1.f - zg) * ng + zg * hprev[r];
        hprev[r] = hn;
        hacc[r] += hn;
        hstg[(bsub + r) * 16 + bl] = (short)f2bf(hn);   // exchange order [b][c]
      }
    }
    __syncthreads();   // S3: hstg ready

    // 5. wave 1: ONE contiguous 512B agent burst + drain + flag (overlaps the
    //    other waves' next-step polls — no joining barrier needed).
    if (wave == 1) {
      ull v = ((const ull*)hstg)[lane];
      __hip_atomic_store(hdst + cg * 64 + lane, v, __ATOMIC_RELAXED,
                         __HIP_MEMORY_SCOPE_AGENT);
      asm volatile("s_waitcnt vmcnt(0)" ::: "memory");   // this wave's stores done
      if (lane == 0)
        __hip_atomic_store(myflag, (unsigned)(s + 1), __ATOMIC_RELAXED,
                           __HIP_MEMORY_SCOPE_AGENT);
    }
    // wave 0: prefetch next step's gx (in flight across the next poll)
    if (wave == 0) {
      int sn = (s + 1 < SEQ) ? (s + 1) : s;
      #pragma unroll
      for (int r = 0; r < 4; ++r) {
        size_t base = ((size_t)(bteam + bsub + r) * SEQ + sn) * G3 + jcol;
        gxr_[r][0] = gx[base];
        gxr_[r][1] = gx[base + 1024];
        gxr_[r][2] = gx[base + 2048];
      }
    }
    // no S4: next iteration's per-wave poll gates everything.
  }

  if (wave == 0) {
    #pragma unroll
    for (int r = 0; r < 4; ++r)
      hsum[(size_t)(bteam + bsub + r) * 1024 + jcol] = hacc[r] * (1.0f / 512.0f);
  }
}

// ---------- kernel 3: mean/logv projections (fp32) ----------
__global__ void proj_kernel(const float* __restrict__ hbar,
                            const float* __restrict__ wm, const float* __restrict__ bm,
                            const float* __restrict__ wl, const float* __restrict__ bl,
                            float* __restrict__ out)
{
  int b = blockIdx.x, t = threadIdx.x;  // 128 threads: 0-63 mean, 64-127 logv
  __shared__ float hrow[1024];
  for (int k = t; k < 1024; k += 128) hrow[k] = hbar[(size_t)b * 1024 + k];
  __syncthreads();
  int j = t & 63;
  const float* w = (t < 64) ? (wm + (size_t)j * 1024) : (wl + (size_t)j * 1024);
  float acc = (t < 64) ? bm[j] : bl[j];
  for (int k = 0; k < 1024; k += 4) {
    f32x4 wv = *(const f32x4*)(w + k);
    acc += hrow[k] * wv[0] + hrow[k+1] * wv[1] + hrow[k+2] * wv[2] + hrow[k+3] * wv[3];
  }
  out[(size_t)((t < 64) ? 0 : 4096) + b * 64 + j] = acc;
}

// ---------- launch ----------
extern "C" void kernel_launch(void* const* d_in, const int* in_sizes, int n_in,
                              void* d_out, int out_size, void* d_ws, size_t ws_size,
                              hipStream_t stream) {
  const int*   ids   = (const int*)d_in[0];
  const float* emb   = (const float*)d_in[1];
  const float* w_ih  = (const float*)d_in[2];
  const float* w_hh  = (const float*)d_in[3];
  const float* b_ih  = (const float*)d_in[4];
  const float* b_hh  = (const float*)d_in[5];
  const float* w_mean= (const float*)d_in[6];
  const float* b_mean= (const float*)d_in[7];
  const float* w_logv= (const float*)d_in[8];
  const float* b_logv= (const float*)d_in[9];
  float* out = (float*)d_out;

  char* ws = (char*)d_ws;
  // ws layout (base section, same as r14)
  unsigned int* flags = (unsigned int*)(ws);                 //     16384 B (4 teams x 64 flags, 64B apart)
  ull* hbuf_q        = (ull*)(ws + 16384);                   //    262144 B [2][4][4096] qwords bf16 ([cg][b][c4])
  float* hsum        = (float*)(ws + 16384 + 262144);        //    262144 B [64][1024] f32
  short* wihb        = (short*)(ws + 16384 + 262144 + 262144);           //   3145728 B
  short* gxbuf       = (short*)(ws + 16384 + 262144 + 262144 + 3145728); // 201326592 B
  size_t base_sz     = 16384 + 262144 + 262144 + 3145728 + 201326592ULL;
  short* embb        = (short*)(ws + base_sz);               //  32768000 B (bf16 emb)
  size_t need_embb   = base_sz + (size_t)VOCAB * EMB * 2;

  // zero flags + h double-buffers (deterministic across graph replays)
  hipMemsetAsync(ws, 0, 16384 + 262144, stream);

  // 0: w_ih -> bf16
  cvt_bf16_kernel<<<(3 * HID * EMB) / 2048, 256, 0, stream>>>(w_ih, wihb);

  // 1: gx GEMM — bf16-A path if workspace allows, else f32-A fallback
  if (ws_size >= need_embb) {
    cvt_bf16_kernel<<<(VOCAB * EMB) / 2048, 256, 0, stream>>>(emb, embb);
    gemm_gx_kernel<<<dim3(24, 256), 256, 0, stream>>>(ids, embb, wihb, gxbuf);
  } else {
    gemm_gx_f32a_kernel<<<dim3(24, 256), 256, 0, stream>>>(ids, emb, wihb, gxbuf);
  }

  // 2: persistent scan — r14 protocol (proven best). All WGs co-resident.
  gru_scan_kernel<<<256, 256, 0, stream>>>(gxbuf, w_hh, b_ih, b_hh, hbuf_q, flags, hsum);
  // 3: projections
  proj_kernel<<<64, 128, 0, stream>>>(hsum, w_mean, b_mean, w_logv, b_logv, out);
}